// Round 13
// baseline (1226.247 us; speedup 1.0000x reference)
//
#include <hip/hip_runtime.h>

typedef unsigned short u16;
typedef short v8s   __attribute__((ext_vector_type(8)));
typedef float f32x4 __attribute__((ext_vector_type(4)));
typedef float f32x2 __attribute__((ext_vector_type(2)));

#define H_ 256
#define B_ 8192
#define NSTEP 31
#define NTHREADS 512
#define NBLOCKS 256
#define AROW 264   // 256 + 8 bf16 pad -> 528B row stride (33x16B, odd) -> conflict-free b128 reads

#define MFMA16(a,b,c) __builtin_amdgcn_mfma_f32_16x16x32_bf16(a,b,c,0,0,0)

// DPP controls
#define DPP_QP_XOR1 0xB1   // quad_perm(1,0,3,2)
#define DPP_QP_XOR2 0x4E   // quad_perm(2,3,0,1)
#define DPP_ROR4    0x124  // row_ror:4
#define DPP_ROR8    0x128  // row_ror:8

template<int CTRL>
__device__ __forceinline__ float dpp_add(float v){
  return v + __int_as_float(
      __builtin_amdgcn_update_dpp(0, __float_as_int(v), CTRL, 0xF, 0xF, true));
}
template<int CTRL>
__device__ __forceinline__ unsigned dpp_mov(unsigned v){
  return (unsigned)__builtin_amdgcn_update_dpp(0, (int)v, CTRL, 0xF, 0xF, true);
}

__device__ __forceinline__ float bperm(float v, int srclane){
  return __int_as_float(
      __builtin_amdgcn_ds_bpermute(srclane*4, __float_as_int(v)));
}

__device__ __forceinline__ u16 f2bf_rne(float f){
  unsigned u = __float_as_uint(f);
  u += 0x7fffu + ((u >> 16) & 1u);
  return (u16)(u >> 16);
}

// ---- workspace layout (u16 units) ----
#define WS_W0   0        // [q][n][j] 4*256*8 = 8192 (W0 padded K->32; k==6 row = b0; k>=7 ZERO)
#define WS_W1   8192     // [n][k]   256*256 = 65536 (Wh[0] transposed)
#define WS_W23  73728    // [l][kc][q][n][j] 2*8*4*256*8 = 131072
#define WS_WO   204800   // [kc][q][nn][j] 8*4*4*8 = 1024
#define WS_TOT  205824

__global__ void prep_kernel(const float* __restrict__ W0,
                            const float* __restrict__ b0,
                            const float* __restrict__ Wh,
                            const float* __restrict__ Wout,
                            u16* __restrict__ ws){
  int i = blockIdx.x * 256 + threadIdx.x;
  if (i < 8192){
    int q = i >> 11, n = (i >> 3) & 255, j = i & 7;
    int k = q*8 + j;
    float v = (k < 6) ? W0[k*H_ + n] : ((k == 6) ? b0[n] : 0.f);
    ws[i] = f2bf_rne(v);
  } else if (i < 73728){
    int r = i - 8192;
    int n = r >> 8, k = r & 255;
    ws[i] = f2bf_rne(Wh[k*H_ + n]);
  } else if (i < 204800){
    int r = i - 73728;
    int l = r >> 16, r2 = r & 65535;
    int kc = r2 >> 13, r3 = r2 & 8191;
    int q = r3 >> 11, n = (r3 >> 3) & 255, j = r3 & 7;
    int k = kc*32 + q*8 + j;
    ws[i] = f2bf_rne(Wh[(1 + l)*H_*H_ + k*H_ + n]);
  } else if (i < WS_TOT){
    int r = i - 204800;
    int kc = r >> 7, q = (r >> 5) & 3, nn = (r >> 3) & 3, j = r & 7;
    int k = kc*32 + q*8 + j;
    ws[i] = f2bf_rne(nn < 3 ? Wout[k*3 + nn] : 0.f);
  }
}

// ---- LDS layout (bytes) ----  (identical to r8)
#define PWROW 10            // partials stride per row in f32x2 units (pad 8->10)
#define OFF_A      0        // 16896
#define OFF_W1     16896    // 135168
#define OFF_WOUT   152064   // 2048
#define OFF_PART   154112   // 32*PWROW*8 = 2560
#define OFF_MR     156672   // 256 (unused; kept for layout stability)
#define OFF_NET    156928   // 512
#define OFF_YCUR   157440   // 512
#define OFF_YSUM   157952   // 512
#define OFF_YSTG   158464   // 512
#define OFF_P      158976   // 512
#define OFF_DTS    159488   // 128
#define LDS_TOTAL  159616

__global__ __launch_bounds__(NTHREADS, 2)
void pinode_kernel(const float* __restrict__ y0g, const float* __restrict__ t_span,
                   const float* __restrict__ params, const float* __restrict__ bhg,
                   const float* __restrict__ ln_gg, const float* __restrict__ ln_bg,
                   const float* __restrict__ boutg, const float* __restrict__ gatep,
                   const u16* __restrict__ ws, float* __restrict__ out)
{
  extern __shared__ char smem[];
  u16*   A    = (u16*)(smem + OFF_A);
  u16*   W1   = (u16*)(smem + OFF_W1);
  u16*   WO   = (u16*)(smem + OFF_WOUT);
  float* part = (float*)(smem + OFF_PART);
  float* net  = (float*)(smem + OFF_NET);
  float* ycur = (float*)(smem + OFF_YCUR);
  float* ysum = (float*)(smem + OFF_YSUM);
  float* ystg = (float*)(smem + OFF_YSTG);
  float* pL   = (float*)(smem + OFF_P);
  float* dts  = (float*)(smem + OFF_DTS);

  const int tid = threadIdx.x;
  const int wave = tid >> 6;
  const int lane = tid & 63;
  const int q    = lane >> 4;
  const int c15  = lane & 15;
  const int colbase = wave * 32;
  const int s0 = blockIdx.x * 32;

  for (int idx = tid; idx < 8192; idx += NTHREADS){
    int n = idx >> 5, ch = idx & 31;
    *(v8s*)(W1 + n*AROW + ch*8) = *(const v8s*)(ws + WS_W1 + n*256 + ch*8);
  }
  if (tid < 128)
    *(v8s*)(WO + tid*8) = *(const v8s*)(ws + WS_WO + tid*8);
  if (tid < 96){
    int s = tid & 31, c = tid >> 5;
    float y = y0g[(s0+s)*3 + c];
    ycur[s*4+c] = y; ystg[s*4+c] = y;
    pL[s*4+c]   = params[(s0+s)*3 + c];
    out[(s0+s)*3 + c] = y;
  }
  if (tid < NSTEP) dts[tid] = t_span[tid+1] - t_span[tid];

  v8s wf[2][8][2];
#pragma unroll
  for (int l = 0; l < 2; ++l)
#pragma unroll
    for (int kc = 0; kc < 8; ++kc)
#pragma unroll
      for (int nt = 0; nt < 2; ++nt)
        wf[l][kc][nt] = *(const v8s*)(ws + WS_W23 +
            (((l*8 + kc)*4 + q)*256 + colbase + nt*16 + c15)*8);

  v8s w0f[2];
#pragma unroll
  for (int nt = 0; nt < 2; ++nt)
    w0f[nt] = *(const v8s*)(ws + WS_W0 + (q*256 + colbase + nt*16 + c15)*8);

  float lng[4][2], lnb[4][2], bia[4][2];
#pragma unroll
  for (int l = 0; l < 4; ++l)
#pragma unroll
    for (int nt = 0; nt < 2; ++nt){
      int col = colbase + nt*16 + c15;
      lng[l][nt] = ln_gg[l*H_ + col];
      lnb[l][nt] = ln_bg[l*H_ + col];
      bia[l][nt] = (l == 0) ? 0.f : bhg[(l-1)*H_ + col];  // b0 folded into W0 row 6
    }
  const float gate = gatep[0];
  const float bo0 = boutg[0], bo1 = boutg[1], bo2 = boutg[2];
  const f32x4 fzero = {0.f, 0.f, 0.f, 0.f};

  // loop-invariant LDS base pointers
  const u16* pa  = A + c15*AROW + q*8;                     // A-frag rows 0..15
  const u16* pw  = W1 + (colbase + c15)*AROW + q*8;        // W1 frag base

  __syncthreads();

  // initial A fill: [y(3), p(3), 1.0 (bias lane), zeros]
  {
    int s = tid >> 4, pr = tid & 15;
    int e0 = pr*2, e1 = e0 + 1;
    float x0 = (e0 < 3) ? ystg[s*4+e0] : ((e0 < 6) ? pL[s*4+e0-3] : (e0 == 6 ? 1.f : 0.f));
    float x1 = (e1 < 3) ? ystg[s*4+e1] : ((e1 < 6) ? pL[s*4+e1-3] : (e1 == 6 ? 1.f : 0.f));
    unsigned pk = (unsigned)f2bf_rne(x0) | ((unsigned)f2bf_rne(x1) << 16);
    *(unsigned*)(A + s*AROW + e0) = pk;
  }
  __syncthreads();

  // LayerNorm + SiLU + bf16 PACK-store to A.
  // vs r8: the 16 scattered u16 stores (4-way bank conflict: row coeff 132≡4
  // mod 32 collapses q/q+2, plus 2 byte-lanes per dword) are replaced by 8
  // u32 stores: lane exchanges bf16 bits with its column-neighbor via DPP
  // XOR1, merges the pair into one dword; even lanes store rows {0,1} of the
  // quad, odd lanes rows {2,3} (r7-proven scheme). New bank pattern
  // 16(q&1)+8*parity+c15/2 = 32 distinct banks, 2 lanes each -> conflict-free.
  auto ln_silu = [&](f32x4 (&acc)[2][2], int li){
    float rs[2][4], rq[2][4];
#pragma unroll
    for (int mt = 0; mt < 2; ++mt)
#pragma unroll
      for (int r = 0; r < 4; ++r){
        float a0 = acc[mt][0][r], a1 = acc[mt][1][r];
        rs[mt][r] = a0 + a1;
        rq[mt][r] = a0*a0 + a1*a1;
      }
    // DPP allreduce over the 16-lane c15 group (pure VALU)
#pragma unroll
    for (int mt = 0; mt < 2; ++mt)
#pragma unroll
      for (int r = 0; r < 4; ++r){
        float s = rs[mt][r], qq = rq[mt][r];
        s = dpp_add<DPP_QP_XOR1>(s);  qq = dpp_add<DPP_QP_XOR1>(qq);
        s = dpp_add<DPP_QP_XOR2>(s);  qq = dpp_add<DPP_QP_XOR2>(qq);
        s = dpp_add<DPP_ROR4>(s);     qq = dpp_add<DPP_ROR4>(qq);
        s = dpp_add<DPP_ROR8>(s);     qq = dpp_add<DPP_ROR8>(qq);
        rs[mt][r] = s; rq[mt][r] = qq;
      }
    if (c15 == 0){
#pragma unroll
      for (int mt = 0; mt < 2; ++mt)
#pragma unroll
        for (int r = 0; r < 4; ++r){
          int row = mt*16 + q*4 + r;
          f32x2 v; v.x = rs[mt][r]; v.y = rq[mt][r];
          *(f32x2*)(part + (row*PWROW + wave)*2) = v;
        }
    }
    __syncthreads();
    // all-lane finalize of row (lane&31); reads are 2-way broadcast across halves
    float rstd_my, mb_my;
    {
      const f32x4* pp = (const f32x4*)(part + (lane & 31)*PWROW*2);
      f32x4 p0 = pp[0], p1 = pp[1], p2 = pp[2], p3 = pp[3];
      float S = p0[0]+p0[2]+p1[0]+p1[2]+p2[0]+p2[2]+p3[0]+p3[2];
      float Q = p0[1]+p0[3]+p1[1]+p1[3]+p2[1]+p2[3]+p3[1]+p3[3];
      float mean = S * (1.f/256.f);
      float var  = Q * (1.f/256.f) - mean*mean;
      rstd_my = rsqrtf(var + 1e-5f);
      mb_my   = -mean * rstd_my;
    }
    const int odd = c15 & 1;
    u16* ppk = A + (q*4 + 2*odd)*AROW + colbase + (c15 & ~1);
#pragma unroll
    for (int mt = 0; mt < 2; ++mt){
      float rstdv[4], mbv[4];
#pragma unroll
      for (int r = 0; r < 4; ++r){
        int row = mt*16 + q*4 + r;
        rstdv[r] = bperm(rstd_my, row);
        mbv[r]   = bperm(mb_my, row);
      }
#pragma unroll
      for (int nt = 0; nt < 2; ++nt){
        unsigned wb[4];
#pragma unroll
        for (int r = 0; r < 4; ++r){
          float t  = acc[mt][nt][r] * rstdv[r] + mbv[r];     // (a-mu)*rstd
          float v  = t * lng[li][nt] + lnb[li][nt];          // *g+b
          float e  = __builtin_amdgcn_exp2f(v * -1.44269504f);
          float sv = v * __builtin_amdgcn_rcpf(1.f + e);     // silu
          unsigned b  = __float_as_uint(sv);
          unsigned nb = dpp_mov<DPP_QP_XOR1>(b);             // neighbor col bits
          wb[r] = odd ? ((nb >> 16) | (b  & 0xFFFF0000u))
                      : ((b  >> 16) | (nb & 0xFFFF0000u));
        }
        unsigned lo = odd ? wb[2] : wb[0];
        unsigned hi = odd ? wb[3] : wb[1];
        *(unsigned*)(ppk + (mt*16)*AROW + nt*16)     = lo;   // row q*4+2*odd
        *(unsigned*)(ppk + (mt*16 + 1)*AROW + nt*16) = hi;   // row q*4+2*odd+1
      }
    }
    __syncthreads();
  };

#pragma unroll 1
  for (int step = 0; step < NSTEP; ++step){
    float dt = dts[step];
#pragma unroll 1
    for (int stage = 0; stage < 4; ++stage){
      f32x4 acc[2][2];

      // ---- layer 0: X(7 used, zero-padded to 32) @ W0' (bias row included) ----
#pragma unroll
      for (int mt = 0; mt < 2; ++mt)
#pragma unroll
        for (int nt = 0; nt < 2; ++nt) acc[mt][nt] = fzero;
      {
        v8s a0 = *(const v8s*)(pa);
        v8s a1 = *(const v8s*)(pa + 16*AROW);
        acc[0][0] = MFMA16(a0, w0f[0], acc[0][0]);
        acc[0][1] = MFMA16(a0, w0f[1], acc[0][1]);
        acc[1][0] = MFMA16(a1, w0f[0], acc[1][0]);
        acc[1][1] = MFMA16(a1, w0f[1], acc[1][1]);
      }
      ln_silu(acc, 0);

      // ---- layer 1: weights from LDS ----
#pragma unroll
      for (int mt = 0; mt < 2; ++mt)
#pragma unroll
        for (int nt = 0; nt < 2; ++nt) acc[mt][nt] = fzero;
#pragma unroll
      for (int kc = 0; kc < 8; ++kc){
        v8s a0 = *(const v8s*)(pa + kc*32);
        v8s a1 = *(const v8s*)(pa + 16*AROW + kc*32);
        v8s bb0 = *(const v8s*)(pw + kc*32);
        v8s bb1 = *(const v8s*)(pw + 16*AROW + kc*32);
        acc[0][0] = MFMA16(a0, bb0, acc[0][0]);
        acc[0][1] = MFMA16(a0, bb1, acc[0][1]);
        acc[1][0] = MFMA16(a1, bb0, acc[1][0]);
        acc[1][1] = MFMA16(a1, bb1, acc[1][1]);
      }
#pragma unroll
      for (int mt = 0; mt < 2; ++mt)
#pragma unroll
        for (int nt = 0; nt < 2; ++nt)
#pragma unroll
          for (int r = 0; r < 4; ++r) acc[mt][nt][r] += bia[1][nt];
      ln_silu(acc, 1);

      // ---- layers 2,3: weights from registers ----
#pragma unroll
      for (int l = 0; l < 2; ++l){
#pragma unroll
        for (int mt = 0; mt < 2; ++mt)
#pragma unroll
          for (int nt = 0; nt < 2; ++nt) acc[mt][nt] = fzero;
#pragma unroll
        for (int kc = 0; kc < 8; ++kc){
          v8s a0 = *(const v8s*)(pa + kc*32);
          v8s a1 = *(const v8s*)(pa + 16*AROW + kc*32);
          acc[0][0] = MFMA16(a0, wf[l][kc][0], acc[0][0]);
          acc[0][1] = MFMA16(a0, wf[l][kc][1], acc[0][1]);
          acc[1][0] = MFMA16(a1, wf[l][kc][0], acc[1][0]);
          acc[1][1] = MFMA16(a1, wf[l][kc][1], acc[1][1]);
        }
#pragma unroll
        for (int mt = 0; mt < 2; ++mt)
#pragma unroll
          for (int nt = 0; nt < 2; ++nt)
#pragma unroll
            for (int r = 0; r < 4; ++r) acc[mt][nt][r] += bia[2+l][nt];
        ln_silu(acc, 2+l);
      }

      // ---- output layer: h @ Wout (waves 0,1) ----
      if (wave < 2){
        f32x4 ao = fzero;
        int nn = c15 < 3 ? c15 : 3;
#pragma unroll
        for (int kc = 0; kc < 8; ++kc){
          v8s a = *(const v8s*)(A + (wave*16 + c15)*AROW + kc*32 + q*8);
          v8s b = *(const v8s*)(WO + ((kc*4 + q)*4 + nn)*8);
          ao = MFMA16(a, b, ao);
        }
        if (c15 < 3){
#pragma unroll
          for (int r = 0; r < 4; ++r)
            net[(wave*16 + q*4 + r)*4 + c15] = ao[r];
        }
      }
      __syncthreads();

      // ---- RK4 bookkeeping + y/params/bias refresh into A ----
      if (tid < 32){
        int s = tid;
        float u = ystg[s*4+0], v = ystg[s*4+1], w = ystg[s*4+2];
        float Om = pL[s*4+0], ga = pL[s*4+2];
        float kk[3];
        kk[0] = -ga*u                      + gate*(net[s*4+0] + bo0);
        kk[1] = -ga*v - Om*w               + gate*(net[s*4+1] + bo1);
        kk[2] = -2.f*ga*(w + 1.f) + Om*v   + gate*(net[s*4+2] + bo2);
#pragma unroll
        for (int c = 0; c < 3; ++c){
          float yc = ycur[s*4+c];
          float k  = kk[c];
          float ys;
          if (stage == 3){
            float accw = ysum[s*4+c] + dt*(1.f/6.f)*k;
            ycur[s*4+c] = accw;
            ys = accw;
            out[(step+1)*(B_*3) + (s0+s)*3 + c] = accw;
          } else {
            float accw = (stage == 0) ? (yc + dt*(1.f/6.f)*k)
                                      : (ysum[s*4+c] + dt*(1.f/3.f)*k);
            ysum[s*4+c] = accw;
            ys = yc + ((stage == 2) ? dt : 0.5f*dt)*k;
          }
          ystg[s*4+c] = ys;
          A[s*AROW + c] = f2bf_rne(ys);
          // refresh params column (layer stores overwrite cols 3..5 every stage)
          A[s*AROW + 3 + c] = f2bf_rne(pL[s*4+c]);
        }
        // refresh bias col 6 = 1.0, col 7 = 0 (layer stores overwrote them)
        *(unsigned*)(A + s*AROW + 6) = 0x00003F80u;
      }
      __syncthreads();
    }
  }
}

extern "C" void kernel_launch(void* const* d_in, const int* in_sizes, int n_in,
                              void* d_out, int out_size, void* d_ws, size_t ws_size,
                              hipStream_t stream) {
  const float* y0     = (const float*)d_in[0];
  const float* t_span = (const float*)d_in[1];
  const float* params = (const float*)d_in[2];
  const float* W0     = (const float*)d_in[3];
  const float* b0     = (const float*)d_in[4];
  const float* Wh     = (const float*)d_in[5];
  const float* bh     = (const float*)d_in[6];
  const float* ln_g   = (const float*)d_in[7];
  const float* ln_b   = (const float*)d_in[8];
  const float* Wout   = (const float*)d_in[9];
  const float* bout   = (const float*)d_in[10];
  const float* gate   = (const float*)d_in[11];
  float* out = (float*)d_out;
  u16* ws = (u16*)d_ws;

  prep_kernel<<<WS_TOT/256, 256, 0, stream>>>(W0, b0, Wh, Wout, ws);

  hipFuncSetAttribute(reinterpret_cast<const void*>(pinode_kernel),
                      hipFuncAttributeMaxDynamicSharedMemorySize, LDS_TOTAL);
  pinode_kernel<<<NBLOCKS, NTHREADS, LDS_TOTAL, stream>>>(
      y0, t_span, params, bh, ln_g, ln_b, bout, gate, ws, out);
}

// Round 14
// 1110.880 us; speedup vs baseline: 1.1039x; 1.1039x over previous
//
#include <hip/hip_runtime.h>

typedef unsigned short u16;
typedef short v8s   __attribute__((ext_vector_type(8)));
typedef float f32x4 __attribute__((ext_vector_type(4)));
typedef float f32x2 __attribute__((ext_vector_type(2)));

#define H_ 256
#define B_ 8192
#define NSTEP 31
#define NTHREADS 512
#define NBLOCKS 256
#define AROW 264   // 256 + 8 bf16 pad -> 528B row stride (33x16B, odd) -> conflict-free b128 reads

#define MFMA16(a,b,c) __builtin_amdgcn_mfma_f32_16x16x32_bf16(a,b,c,0,0,0)

// DPP controls
#define DPP_QP_XOR1 0xB1   // quad_perm(1,0,3,2)
#define DPP_QP_XOR2 0x4E   // quad_perm(2,3,0,1)
#define DPP_ROR4    0x124  // row_ror:4
#define DPP_ROR8    0x128  // row_ror:8

template<int CTRL>
__device__ __forceinline__ float dpp_add(float v){
  return v + __int_as_float(
      __builtin_amdgcn_update_dpp(0, __float_as_int(v), CTRL, 0xF, 0xF, true));
}

__device__ __forceinline__ float bperm(float v, int srclane){
  return __int_as_float(
      __builtin_amdgcn_ds_bpermute(srclane*4, __float_as_int(v)));
}

__device__ __forceinline__ u16 f2bf_rne(float f){
  unsigned u = __float_as_uint(f);
  u += 0x7fffu + ((u >> 16) & 1u);
  return (u16)(u >> 16);
}
__device__ __forceinline__ u16 f2bf_trunc(float f){
  return (u16)(__float_as_uint(f) >> 16);
}

// ---- workspace layout (u16 units) ----
#define WS_W0   0        // [q][n][j] 4*256*8 = 8192 (W0 padded K->32; k==6 row = b0; k>=7 ZERO)
#define WS_W1   8192     // [n][k]   256*256 = 65536 (Wh[0] transposed)
#define WS_W23  73728    // [l][kc][q][n][j] 2*8*4*256*8 = 131072
#define WS_WO   204800   // [kc][q][nn][j] 8*4*4*8 = 1024
#define WS_TOT  205824

__global__ void prep_kernel(const float* __restrict__ W0,
                            const float* __restrict__ b0,
                            const float* __restrict__ Wh,
                            const float* __restrict__ Wout,
                            u16* __restrict__ ws){
  int i = blockIdx.x * 256 + threadIdx.x;
  if (i < 8192){
    int q = i >> 11, n = (i >> 3) & 255, j = i & 7;
    int k = q*8 + j;
    float v = (k < 6) ? W0[k*H_ + n] : ((k == 6) ? b0[n] : 0.f);
    ws[i] = f2bf_rne(v);
  } else if (i < 73728){
    int r = i - 8192;
    int n = r >> 8, k = r & 255;
    ws[i] = f2bf_rne(Wh[k*H_ + n]);
  } else if (i < 204800){
    int r = i - 73728;
    int l = r >> 16, r2 = r & 65535;
    int kc = r2 >> 13, r3 = r2 & 8191;
    int q = r3 >> 11, n = (r3 >> 3) & 255, j = r3 & 7;
    int k = kc*32 + q*8 + j;
    ws[i] = f2bf_rne(Wh[(1 + l)*H_*H_ + k*H_ + n]);
  } else if (i < WS_TOT){
    int r = i - 204800;
    int kc = r >> 7, q = (r >> 5) & 3, nn = (r >> 3) & 3, j = r & 7;
    int k = kc*32 + q*8 + j;
    ws[i] = f2bf_rne(nn < 3 ? Wout[k*3 + nn] : 0.f);
  }
}

// ---- LDS layout (bytes) ----
#define PWROW 10            // partials stride per row in f32x2 units (pad 8->10)
#define OFF_A      0        // 16896
#define OFF_W1     16896    // 135168
#define OFF_WOUT   152064   // 2048
#define OFF_PART   154112   // 32*PWROW*8 = 2560
#define OFF_MR     156672   // 256 (unused; kept for layout stability)
#define OFF_NET    156928   // 512
#define OFF_YCUR   157440   // 512
#define OFF_YSUM   157952   // 512
#define OFF_YSTG   158464   // 1024 (parity double-buffered: cross-thread reads)
#define OFF_P      159488   // 512
#define OFF_DTS    160000   // 128
#define LDS_TOTAL  160128

__global__ __launch_bounds__(NTHREADS, 2)
void pinode_kernel(const float* __restrict__ y0g, const float* __restrict__ t_span,
                   const float* __restrict__ params, const float* __restrict__ bhg,
                   const float* __restrict__ ln_gg, const float* __restrict__ ln_bg,
                   const float* __restrict__ boutg, const float* __restrict__ gatep,
                   const u16* __restrict__ ws, float* __restrict__ out)
{
  extern __shared__ char smem[];
  u16*   A    = (u16*)(smem + OFF_A);
  u16*   W1   = (u16*)(smem + OFF_W1);
  u16*   WO   = (u16*)(smem + OFF_WOUT);
  float* part = (float*)(smem + OFF_PART);
  float* net  = (float*)(smem + OFF_NET);
  float* ycur = (float*)(smem + OFF_YCUR);
  float* ysum = (float*)(smem + OFF_YSUM);
  float* ystg = (float*)(smem + OFF_YSTG);
  float* pL   = (float*)(smem + OFF_P);
  float* dts  = (float*)(smem + OFF_DTS);

  const int tid = threadIdx.x;
  const int wave = tid >> 6;
  const int lane = tid & 63;
  const int q    = lane >> 4;
  const int c15  = lane & 15;
  const int colbase = wave * 32;
  const int s0 = blockIdx.x * 32;

  for (int idx = tid; idx < 8192; idx += NTHREADS){
    int n = idx >> 5, ch = idx & 31;
    *(v8s*)(W1 + n*AROW + ch*8) = *(const v8s*)(ws + WS_W1 + n*256 + ch*8);
  }
  if (tid < 128)
    *(v8s*)(WO + tid*8) = *(const v8s*)(ws + WS_WO + tid*8);
  if (tid < 96){
    int s = tid & 31, c = tid >> 5;
    float y = y0g[(s0+s)*3 + c];
    ycur[s*4+c] = y; ystg[s*4+c] = y;   // ystg parity-0
    pL[s*4+c]   = params[(s0+s)*3 + c];
    out[(s0+s)*3 + c] = y;
  }
  if (tid < NSTEP) dts[tid] = t_span[tid+1] - t_span[tid];

  v8s wf[2][8][2];
#pragma unroll
  for (int l = 0; l < 2; ++l)
#pragma unroll
    for (int kc = 0; kc < 8; ++kc)
#pragma unroll
      for (int nt = 0; nt < 2; ++nt)
        wf[l][kc][nt] = *(const v8s*)(ws + WS_W23 +
            (((l*8 + kc)*4 + q)*256 + colbase + nt*16 + c15)*8);

  v8s w0f[2];
#pragma unroll
  for (int nt = 0; nt < 2; ++nt)
    w0f[nt] = *(const v8s*)(ws + WS_W0 + (q*256 + colbase + nt*16 + c15)*8);

  float lng[4][2], lnb[4][2], bia[4][2];
#pragma unroll
  for (int l = 0; l < 4; ++l)
#pragma unroll
    for (int nt = 0; nt < 2; ++nt){
      int col = colbase + nt*16 + c15;
      lng[l][nt] = ln_gg[l*H_ + col];
      lnb[l][nt] = ln_bg[l*H_ + col];
      bia[l][nt] = (l == 0) ? 0.f : bhg[(l-1)*H_ + col];  // b0 folded into W0 row 6
    }
  const float gate = gatep[0];
  const float bo0 = boutg[0], bo1 = boutg[1], bo2 = boutg[2];
  const f32x4 fzero = {0.f, 0.f, 0.f, 0.f};

  // loop-invariant LDS base pointers
  const u16* pa  = A + c15*AROW + q*8;                     // A-frag rows 0..15
  const u16* pw  = W1 + (colbase + c15)*AROW + q*8;        // W1 frag base
  u16* pstA = A + (q*4)*AROW + colbase + c15;              // LN store base

  __syncthreads();

  // initial A fill: [y(3), p(3), 1.0 (bias lane), zeros]
  {
    int s = tid >> 4, pr = tid & 15;
    int e0 = pr*2, e1 = e0 + 1;
    float x0 = (e0 < 3) ? ystg[s*4+e0] : ((e0 < 6) ? pL[s*4+e0-3] : (e0 == 6 ? 1.f : 0.f));
    float x1 = (e1 < 3) ? ystg[s*4+e1] : ((e1 < 6) ? pL[s*4+e1-3] : (e1 == 6 ? 1.f : 0.f));
    unsigned pk = (unsigned)f2bf_rne(x0) | ((unsigned)f2bf_rne(x1) << 16);
    *(unsigned*)(A + s*AROW + e0) = pk;
  }
  __syncthreads();

  // LayerNorm + SiLU + bf16 store to A (r8 structure: 2 barriers, all-lane finalize)
  auto ln_silu = [&](f32x4 (&acc)[2][2], int li){
    float rs[2][4], rq[2][4];
#pragma unroll
    for (int mt = 0; mt < 2; ++mt)
#pragma unroll
      for (int r = 0; r < 4; ++r){
        float a0 = acc[mt][0][r], a1 = acc[mt][1][r];
        rs[mt][r] = a0 + a1;
        rq[mt][r] = a0*a0 + a1*a1;
      }
    // DPP allreduce over the 16-lane c15 group (pure VALU)
#pragma unroll
    for (int mt = 0; mt < 2; ++mt)
#pragma unroll
      for (int r = 0; r < 4; ++r){
        float s = rs[mt][r], qq = rq[mt][r];
        s = dpp_add<DPP_QP_XOR1>(s);  qq = dpp_add<DPP_QP_XOR1>(qq);
        s = dpp_add<DPP_QP_XOR2>(s);  qq = dpp_add<DPP_QP_XOR2>(qq);
        s = dpp_add<DPP_ROR4>(s);     qq = dpp_add<DPP_ROR4>(qq);
        s = dpp_add<DPP_ROR8>(s);     qq = dpp_add<DPP_ROR8>(qq);
        rs[mt][r] = s; rq[mt][r] = qq;
      }
    if (c15 == 0){
#pragma unroll
      for (int mt = 0; mt < 2; ++mt)
#pragma unroll
        for (int r = 0; r < 4; ++r){
          int row = mt*16 + q*4 + r;
          f32x2 v; v.x = rs[mt][r]; v.y = rq[mt][r];
          *(f32x2*)(part + (row*PWROW + wave)*2) = v;
        }
    }
    __syncthreads();
    // all-lane finalize of row (lane&31); reads are 2-way broadcast across halves
    float rstd_my, mb_my;
    {
      const f32x4* pp = (const f32x4*)(part + (lane & 31)*PWROW*2);
      f32x4 p0 = pp[0], p1 = pp[1], p2 = pp[2], p3 = pp[3];
      float S = p0[0]+p0[2]+p1[0]+p1[2]+p2[0]+p2[2]+p3[0]+p3[2];
      float Q = p0[1]+p0[3]+p1[1]+p1[3]+p2[1]+p2[3]+p3[1]+p3[3];
      float mean = S * (1.f/256.f);
      float var  = Q * (1.f/256.f) - mean*mean;
      rstd_my = rsqrtf(var + 1e-5f);
      mb_my   = -mean * rstd_my;
    }
#pragma unroll
    for (int mt = 0; mt < 2; ++mt)
#pragma unroll
      for (int r = 0; r < 4; ++r){
        int row = mt*16 + q*4 + r;
        float rstd = bperm(rstd_my, row);
        float mb   = bperm(mb_my, row);
#pragma unroll
        for (int nt = 0; nt < 2; ++nt){
          float t  = acc[mt][nt][r] * rstd + mb;             // (a-mu)*rstd
          float v  = t * lng[li][nt] + lnb[li][nt];          // *g+b
          float e  = __builtin_amdgcn_exp2f(v * -1.44269504f);
          float sv = v * __builtin_amdgcn_rcpf(1.f + e);     // silu
          pstA[(mt*16 + r)*AROW + nt*16] = f2bf_trunc(sv);
        }
      }
    __syncthreads();
  };

#pragma unroll 1
  for (int step = 0; step < NSTEP; ++step){
    float dt = dts[step];
#pragma unroll 1
    for (int stage = 0; stage < 4; ++stage){
      f32x4 acc[2][2];

      // ---- layer 0: X(7 used, zero-padded to 32) @ W0' (bias row included) ----
#pragma unroll
      for (int mt = 0; mt < 2; ++mt)
#pragma unroll
        for (int nt = 0; nt < 2; ++nt) acc[mt][nt] = fzero;
      {
        v8s a0 = *(const v8s*)(pa);
        v8s a1 = *(const v8s*)(pa + 16*AROW);
        acc[0][0] = MFMA16(a0, w0f[0], acc[0][0]);
        acc[0][1] = MFMA16(a0, w0f[1], acc[0][1]);
        acc[1][0] = MFMA16(a1, w0f[0], acc[1][0]);
        acc[1][1] = MFMA16(a1, w0f[1], acc[1][1]);
      }
      ln_silu(acc, 0);

      // ---- layer 1: weights from LDS ----
#pragma unroll
      for (int mt = 0; mt < 2; ++mt)
#pragma unroll
        for (int nt = 0; nt < 2; ++nt) acc[mt][nt] = fzero;
#pragma unroll
      for (int kc = 0; kc < 8; ++kc){
        v8s a0 = *(const v8s*)(pa + kc*32);
        v8s a1 = *(const v8s*)(pa + 16*AROW + kc*32);
        v8s bb0 = *(const v8s*)(pw + kc*32);
        v8s bb1 = *(const v8s*)(pw + 16*AROW + kc*32);
        acc[0][0] = MFMA16(a0, bb0, acc[0][0]);
        acc[0][1] = MFMA16(a0, bb1, acc[0][1]);
        acc[1][0] = MFMA16(a1, bb0, acc[1][0]);
        acc[1][1] = MFMA16(a1, bb1, acc[1][1]);
      }
#pragma unroll
      for (int mt = 0; mt < 2; ++mt)
#pragma unroll
        for (int nt = 0; nt < 2; ++nt)
#pragma unroll
          for (int r = 0; r < 4; ++r) acc[mt][nt][r] += bia[1][nt];
      ln_silu(acc, 1);

      // ---- layers 2,3: weights from registers ----
#pragma unroll
      for (int l = 0; l < 2; ++l){
#pragma unroll
        for (int mt = 0; mt < 2; ++mt)
#pragma unroll
          for (int nt = 0; nt < 2; ++nt) acc[mt][nt] = fzero;
#pragma unroll
        for (int kc = 0; kc < 8; ++kc){
          v8s a0 = *(const v8s*)(pa + kc*32);
          v8s a1 = *(const v8s*)(pa + 16*AROW + kc*32);
          acc[0][0] = MFMA16(a0, wf[l][kc][0], acc[0][0]);
          acc[0][1] = MFMA16(a0, wf[l][kc][1], acc[0][1]);
          acc[1][0] = MFMA16(a1, wf[l][kc][0], acc[1][0]);
          acc[1][1] = MFMA16(a1, wf[l][kc][1], acc[1][1]);
        }
#pragma unroll
        for (int mt = 0; mt < 2; ++mt)
#pragma unroll
          for (int nt = 0; nt < 2; ++nt)
#pragma unroll
            for (int r = 0; r < 4; ++r) acc[mt][nt][r] += bia[2+l][nt];
        ln_silu(acc, 2+l);
      }

      // ---- output layer: h @ Wout (waves 0,1) ----
      if (wave < 2){
        f32x4 ao = fzero;
        int nn = c15 < 3 ? c15 : 3;
#pragma unroll
        for (int kc = 0; kc < 8; ++kc){
          v8s a = *(const v8s*)(A + (wave*16 + c15)*AROW + kc*32 + q*8);
          v8s b = *(const v8s*)(WO + ((kc*4 + q)*4 + nn)*8);
          ao = MFMA16(a, b, ao);
        }
        if (c15 < 3){
#pragma unroll
          for (int r = 0; r < 4; ++r)
            net[(wave*16 + q*4 + r)*4 + c15] = ao[r];
        }
      }
      __syncthreads();

      // ---- RK4 bookkeeping: parallel over (sample, component) ----
      // vs r8: the tid<32 serial 3-component chain is split over 96 threads,
      // one (s,c) each. The only cross-thread hazard (thread (s,1) reads
      // ystg[s][2] while (s,2) writes it, possibly cross-wave) is removed by
      // parity double-buffering ystg: read [stage&1], write [stage&1 ^ 1].
      // ycur/ysum are only ever self-read -> single-buffered.
      {
        const int cur = (stage & 1)*128, nx = ((stage & 1) ^ 1)*128;
        if (tid < 96){
          int s = tid & 31, c = tid >> 5;
          float Om = pL[s*4+0], ga = pL[s*4+2];
          float yi  = ystg[cur + s*4+c];
          float oth = ystg[cur + s*4 + ((c == 1) ? 2 : 1)];
          float kA = (c == 2) ? (Om*oth - 2.f*ga*(yi + 1.f))
                              : (-ga*yi - ((c == 1) ? Om*oth : 0.f));
          const float boc = (c == 0) ? bo0 : ((c == 1) ? bo1 : bo2);
          float k = kA + gate*(net[s*4+c] + boc);
          float yc = ycur[s*4+c];
          float ys;
          if (stage == 3){
            float accw = ysum[s*4+c] + dt*(1.f/6.f)*k;
            ycur[s*4+c] = accw;
            ys = accw;
            out[(step+1)*(B_*3) + (s0+s)*3 + c] = accw;
          } else {
            float accw = (stage == 0) ? (yc + dt*(1.f/6.f)*k)
                                      : (ysum[s*4+c] + dt*(1.f/3.f)*k);
            ysum[s*4+c] = accw;
            ys = yc + ((stage == 2) ? dt : 0.5f*dt)*k;
          }
          ystg[nx + s*4+c] = ys;
          A[s*AROW + c] = f2bf_rne(ys);
          // refresh params column (layer stores overwrite cols 3..5 every stage)
          A[s*AROW + 3 + c] = f2bf_rne(pL[s*4+c]);
        } else if (tid < 128){
          // refresh bias col 6 = 1.0, col 7 = 0 (layer stores overwrote them)
          int s = tid - 96;
          *(unsigned*)(A + s*AROW + 6) = 0x00003F80u;
        }
      }
      __syncthreads();
    }
  }
}

extern "C" void kernel_launch(void* const* d_in, const int* in_sizes, int n_in,
                              void* d_out, int out_size, void* d_ws, size_t ws_size,
                              hipStream_t stream) {
  const float* y0     = (const float*)d_in[0];
  const float* t_span = (const float*)d_in[1];
  const float* params = (const float*)d_in[2];
  const float* W0     = (const float*)d_in[3];
  const float* b0     = (const float*)d_in[4];
  const float* Wh     = (const float*)d_in[5];
  const float* bh     = (const float*)d_in[6];
  const float* ln_g   = (const float*)d_in[7];
  const float* ln_b   = (const float*)d_in[8];
  const float* Wout   = (const float*)d_in[9];
  const float* bout   = (const float*)d_in[10];
  const float* gate   = (const float*)d_in[11];
  float* out = (float*)d_out;
  u16* ws = (u16*)d_ws;

  prep_kernel<<<WS_TOT/256, 256, 0, stream>>>(W0, b0, Wh, Wout, ws);

  hipFuncSetAttribute(reinterpret_cast<const void*>(pinode_kernel),
                      hipFuncAttributeMaxDynamicSharedMemorySize, LDS_TOTAL);
  pinode_kernel<<<NBLOCKS, NTHREADS, LDS_TOTAL, stream>>>(
      y0, t_span, params, bh, ln_g, ln_b, bout, gate, ws, out);
}

// Round 15
// 1064.968 us; speedup vs baseline: 1.1514x; 1.0431x over previous
//
#include <hip/hip_runtime.h>

typedef unsigned short u16;
typedef short v8s   __attribute__((ext_vector_type(8)));
typedef float f32x4 __attribute__((ext_vector_type(4)));
typedef float f32x2 __attribute__((ext_vector_type(2)));

#define H_ 256
#define B_ 8192
#define NSTEP 31
#define NTHREADS 512
#define NBLOCKS 256
#define AROW 264   // 256 + 8 bf16 pad -> 528B row stride (33x16B, odd) -> conflict-free b128 reads

#define MFMA16(a,b,c) __builtin_amdgcn_mfma_f32_16x16x32_bf16(a,b,c,0,0,0)

// DPP controls
#define DPP_QP_XOR1 0xB1   // quad_perm(1,0,3,2)
#define DPP_QP_XOR2 0x4E   // quad_perm(2,3,0,1)
#define DPP_ROR4    0x124  // row_ror:4
#define DPP_ROR8    0x128  // row_ror:8

template<int CTRL>
__device__ __forceinline__ float dpp_add(float v){
  return v + __int_as_float(
      __builtin_amdgcn_update_dpp(0, __float_as_int(v), CTRL, 0xF, 0xF, true));
}

__device__ __forceinline__ float bperm(float v, int srclane){
  return __int_as_float(
      __builtin_amdgcn_ds_bpermute(srclane*4, __float_as_int(v)));
}

__device__ __forceinline__ u16 f2bf_rne(float f){
  unsigned u = __float_as_uint(f);
  u += 0x7fffu + ((u >> 16) & 1u);
  return (u16)(u >> 16);
}
__device__ __forceinline__ u16 f2bf_trunc(float f){
  return (u16)(__float_as_uint(f) >> 16);
}

// ---- workspace layout (u16 units) ----
#define WS_W0   0        // [q][n][j] 4*256*8 = 8192 (W0 padded K->32; k==6 row = b0; k>=7 ZERO)
#define WS_W1   8192     // [n][k]   256*256 = 65536 (Wh[0] transposed)
#define WS_W23  73728    // [l][kc][q][n][j] 2*8*4*256*8 = 131072
#define WS_WO   204800   // [kc][q][nn][j] 8*4*4*8 = 1024
#define WS_TOT  205824

__global__ void prep_kernel(const float* __restrict__ W0,
                            const float* __restrict__ b0,
                            const float* __restrict__ Wh,
                            const float* __restrict__ Wout,
                            u16* __restrict__ ws){
  int i = blockIdx.x * 256 + threadIdx.x;
  if (i < 8192){
    int q = i >> 11, n = (i >> 3) & 255, j = i & 7;
    int k = q*8 + j;
    float v = (k < 6) ? W0[k*H_ + n] : ((k == 6) ? b0[n] : 0.f);
    ws[i] = f2bf_rne(v);
  } else if (i < 73728){
    int r = i - 8192;
    int n = r >> 8, k = r & 255;
    ws[i] = f2bf_rne(Wh[k*H_ + n]);
  } else if (i < 204800){
    int r = i - 73728;
    int l = r >> 16, r2 = r & 65535;
    int kc = r2 >> 13, r3 = r2 & 8191;
    int q = r3 >> 11, n = (r3 >> 3) & 255, j = r3 & 7;
    int k = kc*32 + q*8 + j;
    ws[i] = f2bf_rne(Wh[(1 + l)*H_*H_ + k*H_ + n]);
  } else if (i < WS_TOT){
    int r = i - 204800;
    int kc = r >> 7, q = (r >> 5) & 3, nn = (r >> 3) & 3, j = r & 7;
    int k = kc*32 + q*8 + j;
    ws[i] = f2bf_rne(nn < 3 ? Wout[k*3 + nn] : 0.f);
  }
}

// ---- LDS layout (bytes) ----
#define PWROW 10            // partials stride per row in f32x2 units (pad 8->10)
#define OFF_A      0        // 16896
#define OFF_W1     16896    // 135168
#define OFF_WOUT   152064   // 2048
#define OFF_PART   154112   // 32*PWROW*8 = 2560
#define OFF_MR     156672   // 256 (unused; kept for layout stability)
#define OFF_NET    156928   // [kp:4][row:32][c:4] f32 = 2048 (K-split out partials)
#define OFF_YCUR   158976   // 512
#define OFF_YSUM   159488   // 512
#define OFF_YSTG   160000   // 1024 (parity double-buffered: cross-thread reads)
#define OFF_P      161024   // 512
#define OFF_DTS    161536   // 128
#define LDS_TOTAL  161664

__global__ __launch_bounds__(NTHREADS, 2)
void pinode_kernel(const float* __restrict__ y0g, const float* __restrict__ t_span,
                   const float* __restrict__ params, const float* __restrict__ bhg,
                   const float* __restrict__ ln_gg, const float* __restrict__ ln_bg,
                   const float* __restrict__ boutg, const float* __restrict__ gatep,
                   const u16* __restrict__ ws, float* __restrict__ out)
{
  extern __shared__ char smem[];
  u16*   A    = (u16*)(smem + OFF_A);
  u16*   W1   = (u16*)(smem + OFF_W1);
  u16*   WO   = (u16*)(smem + OFF_WOUT);
  float* part = (float*)(smem + OFF_PART);
  float* net  = (float*)(smem + OFF_NET);
  float* ycur = (float*)(smem + OFF_YCUR);
  float* ysum = (float*)(smem + OFF_YSUM);
  float* ystg = (float*)(smem + OFF_YSTG);
  float* pL   = (float*)(smem + OFF_P);
  float* dts  = (float*)(smem + OFF_DTS);

  const int tid = threadIdx.x;
  const int wave = tid >> 6;
  const int lane = tid & 63;
  const int q    = lane >> 4;
  const int c15  = lane & 15;
  const int colbase = wave * 32;
  const int s0 = blockIdx.x * 32;

  for (int idx = tid; idx < 8192; idx += NTHREADS){
    int n = idx >> 5, ch = idx & 31;
    *(v8s*)(W1 + n*AROW + ch*8) = *(const v8s*)(ws + WS_W1 + n*256 + ch*8);
  }
  if (tid < 128)
    *(v8s*)(WO + tid*8) = *(const v8s*)(ws + WS_WO + tid*8);
  if (tid < 96){
    int s = tid & 31, c = tid >> 5;
    float y = y0g[(s0+s)*3 + c];
    ycur[s*4+c] = y; ystg[s*4+c] = y;   // ystg parity-0
    pL[s*4+c]   = params[(s0+s)*3 + c];
    out[(s0+s)*3 + c] = y;
  }
  if (tid < NSTEP) dts[tid] = t_span[tid+1] - t_span[tid];

  v8s wf[2][8][2];
#pragma unroll
  for (int l = 0; l < 2; ++l)
#pragma unroll
    for (int kc = 0; kc < 8; ++kc)
#pragma unroll
      for (int nt = 0; nt < 2; ++nt)
        wf[l][kc][nt] = *(const v8s*)(ws + WS_W23 +
            (((l*8 + kc)*4 + q)*256 + colbase + nt*16 + c15)*8);

  v8s w0f[2];
#pragma unroll
  for (int nt = 0; nt < 2; ++nt)
    w0f[nt] = *(const v8s*)(ws + WS_W0 + (q*256 + colbase + nt*16 + c15)*8);

  float lng[4][2], lnb[4][2], bia[4][2];
#pragma unroll
  for (int l = 0; l < 4; ++l)
#pragma unroll
    for (int nt = 0; nt < 2; ++nt){
      int col = colbase + nt*16 + c15;
      lng[l][nt] = ln_gg[l*H_ + col];
      lnb[l][nt] = ln_bg[l*H_ + col];
      bia[l][nt] = (l == 0) ? 0.f : bhg[(l-1)*H_ + col];  // b0 folded into W0 row 6
    }
  const float gate = gatep[0];
  const float bo0 = boutg[0], bo1 = boutg[1], bo2 = boutg[2];
  const f32x4 fzero = {0.f, 0.f, 0.f, 0.f};

  // loop-invariant LDS base pointers
  const u16* pa  = A + c15*AROW + q*8;                     // A-frag rows 0..15
  const u16* pw  = W1 + (colbase + c15)*AROW + q*8;        // W1 frag base
  u16* pstA = A + (q*4)*AROW + colbase + c15;              // LN store base

  __syncthreads();

  // initial A fill: [y(3), p(3), 1.0 (bias lane), zeros]
  {
    int s = tid >> 4, pr = tid & 15;
    int e0 = pr*2, e1 = e0 + 1;
    float x0 = (e0 < 3) ? ystg[s*4+e0] : ((e0 < 6) ? pL[s*4+e0-3] : (e0 == 6 ? 1.f : 0.f));
    float x1 = (e1 < 3) ? ystg[s*4+e1] : ((e1 < 6) ? pL[s*4+e1-3] : (e1 == 6 ? 1.f : 0.f));
    unsigned pk = (unsigned)f2bf_rne(x0) | ((unsigned)f2bf_rne(x1) << 16);
    *(unsigned*)(A + s*AROW + e0) = pk;
  }
  __syncthreads();

  // LayerNorm + SiLU + bf16 store to A (r8 structure: 2 barriers, all-lane finalize)
  auto ln_silu = [&](f32x4 (&acc)[2][2], int li){
    float rs[2][4], rq[2][4];
#pragma unroll
    for (int mt = 0; mt < 2; ++mt)
#pragma unroll
      for (int r = 0; r < 4; ++r){
        float a0 = acc[mt][0][r], a1 = acc[mt][1][r];
        rs[mt][r] = a0 + a1;
        rq[mt][r] = a0*a0 + a1*a1;
      }
    // DPP allreduce over the 16-lane c15 group (pure VALU)
#pragma unroll
    for (int mt = 0; mt < 2; ++mt)
#pragma unroll
      for (int r = 0; r < 4; ++r){
        float s = rs[mt][r], qq = rq[mt][r];
        s = dpp_add<DPP_QP_XOR1>(s);  qq = dpp_add<DPP_QP_XOR1>(qq);
        s = dpp_add<DPP_QP_XOR2>(s);  qq = dpp_add<DPP_QP_XOR2>(qq);
        s = dpp_add<DPP_ROR4>(s);     qq = dpp_add<DPP_ROR4>(qq);
        s = dpp_add<DPP_ROR8>(s);     qq = dpp_add<DPP_ROR8>(qq);
        rs[mt][r] = s; rq[mt][r] = qq;
      }
    if (c15 == 0){
#pragma unroll
      for (int mt = 0; mt < 2; ++mt)
#pragma unroll
        for (int r = 0; r < 4; ++r){
          int row = mt*16 + q*4 + r;
          f32x2 v; v.x = rs[mt][r]; v.y = rq[mt][r];
          *(f32x2*)(part + (row*PWROW + wave)*2) = v;
        }
    }
    __syncthreads();
    // all-lane finalize of row (lane&31); reads are 2-way broadcast across halves
    float rstd_my, mb_my;
    {
      const f32x4* pp = (const f32x4*)(part + (lane & 31)*PWROW*2);
      f32x4 p0 = pp[0], p1 = pp[1], p2 = pp[2], p3 = pp[3];
      float S = p0[0]+p0[2]+p1[0]+p1[2]+p2[0]+p2[2]+p3[0]+p3[2];
      float Q = p0[1]+p0[3]+p1[1]+p1[3]+p2[1]+p2[3]+p3[1]+p3[3];
      float mean = S * (1.f/256.f);
      float var  = Q * (1.f/256.f) - mean*mean;
      rstd_my = rsqrtf(var + 1e-5f);
      mb_my   = -mean * rstd_my;
    }
#pragma unroll
    for (int mt = 0; mt < 2; ++mt)
#pragma unroll
      for (int r = 0; r < 4; ++r){
        int row = mt*16 + q*4 + r;
        float rstd = bperm(rstd_my, row);
        float mb   = bperm(mb_my, row);
#pragma unroll
        for (int nt = 0; nt < 2; ++nt){
          float t  = acc[mt][nt][r] * rstd + mb;             // (a-mu)*rstd
          float v  = t * lng[li][nt] + lnb[li][nt];          // *g+b
          float e  = __builtin_amdgcn_exp2f(v * -1.44269504f);
          float sv = v * __builtin_amdgcn_rcpf(1.f + e);     // silu
          pstA[(mt*16 + r)*AROW + nt*16] = f2bf_trunc(sv);
        }
      }
    __syncthreads();
  };

#pragma unroll 1
  for (int step = 0; step < NSTEP; ++step){
    float dt = dts[step];
#pragma unroll 1
    for (int stage = 0; stage < 4; ++stage){
      f32x4 acc[2][2];

      // ---- layer 0: X(7 used, zero-padded to 32) @ W0' (bias row included) ----
#pragma unroll
      for (int mt = 0; mt < 2; ++mt)
#pragma unroll
        for (int nt = 0; nt < 2; ++nt) acc[mt][nt] = fzero;
      {
        v8s a0 = *(const v8s*)(pa);
        v8s a1 = *(const v8s*)(pa + 16*AROW);
        acc[0][0] = MFMA16(a0, w0f[0], acc[0][0]);
        acc[0][1] = MFMA16(a0, w0f[1], acc[0][1]);
        acc[1][0] = MFMA16(a1, w0f[0], acc[1][0]);
        acc[1][1] = MFMA16(a1, w0f[1], acc[1][1]);
      }
      ln_silu(acc, 0);

      // ---- layer 1: weights from LDS ----
#pragma unroll
      for (int mt = 0; mt < 2; ++mt)
#pragma unroll
        for (int nt = 0; nt < 2; ++nt) acc[mt][nt] = fzero;
#pragma unroll
      for (int kc = 0; kc < 8; ++kc){
        v8s a0 = *(const v8s*)(pa + kc*32);
        v8s a1 = *(const v8s*)(pa + 16*AROW + kc*32);
        v8s bb0 = *(const v8s*)(pw + kc*32);
        v8s bb1 = *(const v8s*)(pw + 16*AROW + kc*32);
        acc[0][0] = MFMA16(a0, bb0, acc[0][0]);
        acc[0][1] = MFMA16(a0, bb1, acc[0][1]);
        acc[1][0] = MFMA16(a1, bb0, acc[1][0]);
        acc[1][1] = MFMA16(a1, bb1, acc[1][1]);
      }
#pragma unroll
      for (int mt = 0; mt < 2; ++mt)
#pragma unroll
        for (int nt = 0; nt < 2; ++nt)
#pragma unroll
          for (int r = 0; r < 4; ++r) acc[mt][nt][r] += bia[1][nt];
      ln_silu(acc, 1);

      // ---- layers 2,3: weights from registers ----
#pragma unroll
      for (int l = 0; l < 2; ++l){
#pragma unroll
        for (int mt = 0; mt < 2; ++mt)
#pragma unroll
          for (int nt = 0; nt < 2; ++nt) acc[mt][nt] = fzero;
#pragma unroll
        for (int kc = 0; kc < 8; ++kc){
          v8s a0 = *(const v8s*)(pa + kc*32);
          v8s a1 = *(const v8s*)(pa + 16*AROW + kc*32);
          acc[0][0] = MFMA16(a0, wf[l][kc][0], acc[0][0]);
          acc[0][1] = MFMA16(a0, wf[l][kc][1], acc[0][1]);
          acc[1][0] = MFMA16(a1, wf[l][kc][0], acc[1][0]);
          acc[1][1] = MFMA16(a1, wf[l][kc][1], acc[1][1]);
        }
#pragma unroll
        for (int mt = 0; mt < 2; ++mt)
#pragma unroll
          for (int nt = 0; nt < 2; ++nt)
#pragma unroll
            for (int r = 0; r < 4; ++r) acc[mt][nt][r] += bia[2+l][nt];
        ln_silu(acc, 2+l);
      }

      // ---- output layer: h @ Wout, K-SPLIT across ALL 8 waves ----
      // vs r14: waves 0-1 each did 8 dependent MFMAs while 6 waves (3 of 4
      // SIMDs) idled. Now wave w = (row-group g = w&1, kc-pair kp = w>>1)
      // does 2 accumulating MFMAs and writes a K-partial; RK4 sums 4 partials.
      // Critical path ~4x shorter, all SIMDs busy.
      {
        const int g  = wave & 1;
        const int kp = wave >> 1;
        const int nn = c15 < 3 ? c15 : 3;
        const u16* pao = A + (g*16 + c15)*AROW + kp*64 + q*8;
        v8s a0 = *(const v8s*)(pao);
        v8s a1 = *(const v8s*)(pao + 32);
        v8s b0 = *(const v8s*)(WO + (((kp*2    )*4 + q)*4 + nn)*8);
        v8s b1 = *(const v8s*)(WO + (((kp*2 + 1)*4 + q)*4 + nn)*8);
        f32x4 ao = MFMA16(a1, b1, MFMA16(a0, b0, fzero));
        if (c15 < 3){
#pragma unroll
          for (int r = 0; r < 4; ++r)
            net[kp*128 + (g*16 + q*4 + r)*4 + c15] = ao[r];
        }
      }
      __syncthreads();

      // ---- RK4 bookkeeping: parallel over (sample, component) ----
      // (r14 structure; net is now a 4-way K-partial sum)
      {
        const int cur = (stage & 1)*128, nx = ((stage & 1) ^ 1)*128;
        if (tid < 96){
          int s = tid & 31, c = tid >> 5;
          float Om = pL[s*4+0], ga = pL[s*4+2];
          float yi  = ystg[cur + s*4+c];
          float oth = ystg[cur + s*4 + ((c == 1) ? 2 : 1)];
          float kA = (c == 2) ? (Om*oth - 2.f*ga*(yi + 1.f))
                              : (-ga*yi - ((c == 1) ? Om*oth : 0.f));
          const float boc = (c == 0) ? bo0 : ((c == 1) ? bo1 : bo2);
          float netv = (net[s*4+c] + net[128 + s*4+c])
                     + (net[256 + s*4+c] + net[384 + s*4+c]);
          float k = kA + gate*(netv + boc);
          float yc = ycur[s*4+c];
          float ys;
          if (stage == 3){
            float accw = ysum[s*4+c] + dt*(1.f/6.f)*k;
            ycur[s*4+c] = accw;
            ys = accw;
            out[(step+1)*(B_*3) + (s0+s)*3 + c] = accw;
          } else {
            float accw = (stage == 0) ? (yc + dt*(1.f/6.f)*k)
                                      : (ysum[s*4+c] + dt*(1.f/3.f)*k);
            ysum[s*4+c] = accw;
            ys = yc + ((stage == 2) ? dt : 0.5f*dt)*k;
          }
          ystg[nx + s*4+c] = ys;
          A[s*AROW + c] = f2bf_rne(ys);
          // refresh params column (layer stores overwrite cols 3..5 every stage)
          A[s*AROW + 3 + c] = f2bf_rne(pL[s*4+c]);
        } else if (tid < 128){
          // refresh bias col 6 = 1.0, col 7 = 0 (layer stores overwrote them)
          int s = tid - 96;
          *(unsigned*)(A + s*AROW + 6) = 0x00003F80u;
        }
      }
      __syncthreads();
    }
  }
}

extern "C" void kernel_launch(void* const* d_in, const int* in_sizes, int n_in,
                              void* d_out, int out_size, void* d_ws, size_t ws_size,
                              hipStream_t stream) {
  const float* y0     = (const float*)d_in[0];
  const float* t_span = (const float*)d_in[1];
  const float* params = (const float*)d_in[2];
  const float* W0     = (const float*)d_in[3];
  const float* b0     = (const float*)d_in[4];
  const float* Wh     = (const float*)d_in[5];
  const float* bh     = (const float*)d_in[6];
  const float* ln_g   = (const float*)d_in[7];
  const float* ln_b   = (const float*)d_in[8];
  const float* Wout   = (const float*)d_in[9];
  const float* bout   = (const float*)d_in[10];
  const float* gate   = (const float*)d_in[11];
  float* out = (float*)d_out;
  u16* ws = (u16*)d_ws;

  prep_kernel<<<WS_TOT/256, 256, 0, stream>>>(W0, b0, Wh, Wout, ws);

  hipFuncSetAttribute(reinterpret_cast<const void*>(pinode_kernel),
                      hipFuncAttributeMaxDynamicSharedMemorySize, LDS_TOTAL);
  pinode_kernel<<<NBLOCKS, NTHREADS, LDS_TOTAL, stream>>>(
      y0, t_span, params, bh, ln_g, ln_b, bout, gate, ws, out);
}